// Round 6
// baseline (1331.802 us; speedup 1.0000x reference)
//
#include <hip/hip_runtime.h>
#include <cstdint>
#include <cstddef>

typedef _Float16 f16;
typedef _Float16 f16x4 __attribute__((ext_vector_type(4)));
typedef _Float16 f16x8 __attribute__((ext_vector_type(8)));
typedef float floatx4 __attribute__((ext_vector_type(4)));

#define MFMA32(a,b,c) __builtin_amdgcn_mfma_f32_16x16x32_f16((a),(b),(c),0,0,0)

#define ROWS 8192            // B*L
#define NCHUNK 128           // L/CS
// qkvgHi column order (reordered!): k [0,512) | v [512,1536) | q [1536,2048) | g [2048,3072)
// kvLo covers cols [0,1536) (k,v lo parts), row stride 1536.
static constexpr float QSCALE = 0.08838834764831845f; // 128^-0.5

static __device__ __forceinline__ float sigmoidf_(float x) { return 1.0f / (1.0f + expf(-x)); }

// ---------------------------------------------------------------------------
// 1) Weights -> f16. Wcat rows (reordered): [0,512)=Wk [512,1536)=Wv
//    [1536,2048)=Wq [2048,3072)=Wg.  hi for all; lo only rows<1536 (k,v).
//    Wo -> hi only.
// ---------------------------------------------------------------------------
__global__ __launch_bounds__(256) void wconv_kernel(
    const float* __restrict__ Wq, const float* __restrict__ Wk,
    const float* __restrict__ Wv, const float* __restrict__ Wg,
    const float* __restrict__ Wo,
    f16* __restrict__ WcatHi, f16* __restrict__ WcatLoKV, f16* __restrict__ WoHi) {
  int tid = blockIdx.x * 256 + threadIdx.x;   // 524288 threads, 8 elems each
  int e8 = tid * 8;
  if (e8 < 3145728) {
    int row = e8 >> 10, col = e8 & 1023;
    const float* src;
    if (row < 512)       src = Wk + (size_t)row * 1024 + col;
    else if (row < 1536) src = Wv + (size_t)(row - 512) * 1024 + col;
    else if (row < 2048) src = Wq + (size_t)(row - 1536) * 1024 + col;
    else                 src = Wg + (size_t)(row - 2048) * 1024 + col;
    f16 thi[8] __attribute__((aligned(16)));
    f16 tlo[8] __attribute__((aligned(16)));
#pragma unroll
    for (int j = 0; j < 8; j++) {
      float x = src[j];
      f16 h = (f16)x;
      thi[j] = h;
      tlo[j] = (f16)(x - (float)h);
    }
    *(uint4*)&WcatHi[e8] = *(const uint4*)thi;
    if (row < 1536) *(uint4*)&WcatLoKV[e8] = *(const uint4*)tlo;
  } else {
    int idx = e8 - 3145728;
    f16 t[8] __attribute__((aligned(16)));
#pragma unroll
    for (int j = 0; j < 8; j++) t[j] = (f16)Wo[idx + j];
    *(uint4*)&WoHi[idx] = *(const uint4*)t;
  }
}

// ---------------------------------------------------------------------------
// 2) Causal depthwise conv1d (K=4) + SiLU -> x hi/lo fp16 pair [8192][1024]
// ---------------------------------------------------------------------------
__global__ __launch_bounds__(256) void conv_kernel(
    const float* __restrict__ hs, const float* __restrict__ cw,
    f16* __restrict__ xhi, f16* __restrict__ xlo) {
  int row = blockIdx.x;              // b*2048 + l
  int b = row >> 11, l = row & 2047;
  int d = threadIdx.x * 4;
  floatx4 w0 = *(const floatx4*)&cw[(d + 0) * 4];
  floatx4 w1 = *(const floatx4*)&cw[(d + 1) * 4];
  floatx4 w2 = *(const floatx4*)&cw[(d + 2) * 4];
  floatx4 w3 = *(const floatx4*)&cw[(d + 3) * 4];
  floatx4 acc = {0.f, 0.f, 0.f, 0.f};
#pragma unroll
  for (int j = 0; j < 4; j++) {
    int ls = l - 3 + j;
    if (ls < 0) continue;
    floatx4 hv = *(const floatx4*)&hs[(size_t)(b * 2048 + ls) * 1024 + d];
    acc[0] += hv[0] * w0[j];
    acc[1] += hv[1] * w1[j];
    acc[2] += hv[2] * w2[j];
    acc[3] += hv[3] * w3[j];
  }
  f16 ohi[4] __attribute__((aligned(8)));
  f16 olo[4] __attribute__((aligned(8)));
#pragma unroll
  for (int q = 0; q < 4; q++) {
    float y = acc[q] * sigmoidf_(acc[q]);
    f16 h = (f16)y;
    ohi[q] = h;
    olo[q] = (f16)(y - (float)h);
  }
  *(uint2*)&xhi[(size_t)row * 1024 + d] = *(const uint2*)ohi;
  *(uint2*)&xlo[(size_t)row * 1024 + d] = *(const uint2*)olo;
}

// ---------------------------------------------------------------------------
// 3) beta[row][h] = sigmoid(x . Wb[h])  (fp32, x = hi+lo)
// ---------------------------------------------------------------------------
__global__ __launch_bounds__(256) void beta_kernel(
    const f16* __restrict__ xhi, const f16* __restrict__ xlo,
    const float* __restrict__ Wb, float* __restrict__ betaf) {
  int row = blockIdx.x;
  int t = threadIdx.x;
  __shared__ floatx4 red[256];
  int c = t * 4;
  float xv[4];
#pragma unroll
  for (int j = 0; j < 4; j++)
    xv[j] = (float)xhi[(size_t)row * 1024 + c + j] + (float)xlo[(size_t)row * 1024 + c + j];
  floatx4 p = {0.f, 0.f, 0.f, 0.f};
#pragma unroll
  for (int hh = 0; hh < 4; hh++) {
    const float* wr = Wb + hh * 1024 + c;
    p[hh] = xv[0] * wr[0] + xv[1] * wr[1] + xv[2] * wr[2] + xv[3] * wr[3];
  }
  red[t] = p;
  __syncthreads();
  for (int s = 128; s > 0; s >>= 1) {
    if (t < s) red[t] += red[t + s];
    __syncthreads();
  }
  if (t < 4) betaf[(size_t)row * 4 + t] = sigmoidf_(red[0][t]);
}

// ---------------------------------------------------------------------------
// 4a) hi/lo GEMM for k,v cols: C = (Ahi+Alo) @ (Bhi+Blo)^T, 3 MFMAs/tile.
//     ChHi row stride 3072 (into qkvgHi cols [0,1536)), ChLo stride 1536.
// ---------------------------------------------------------------------------
__global__ __launch_bounds__(256) void gemm_hilo_kv(
    const f16* __restrict__ Ahi, const f16* __restrict__ Alo,
    const f16* __restrict__ Bhi, const f16* __restrict__ Blo,
    f16* __restrict__ ChHi, f16* __restrict__ ChLo, int K) {
  __shared__ __attribute__((aligned(16))) f16 AsH[128][40];
  __shared__ __attribute__((aligned(16))) f16 AsL[128][40];
  __shared__ __attribute__((aligned(16))) f16 BsH[128][40];
  __shared__ __attribute__((aligned(16))) f16 BsL[128][40];
  const int t = threadIdx.x;
  const int lane = t & 63, wave = t >> 6;
  const int lc = lane & 15, quad = lane >> 4;
  const int wm = (wave >> 1) * 64, wn = (wave & 1) * 64;
  const int m0 = blockIdx.y * 128, n0 = blockIdx.x * 128;
  const int r = t >> 2, c8 = (t & 3) * 8;
  floatx4 acc[4][4] = {};
  for (int kt = 0; kt < K; kt += 32) {
    __syncthreads();
    *(uint4*)&AsH[r][c8]      = *(const uint4*)&Ahi[(size_t)(m0 + r) * K + kt + c8];
    *(uint4*)&AsH[r + 64][c8] = *(const uint4*)&Ahi[(size_t)(m0 + r + 64) * K + kt + c8];
    *(uint4*)&AsL[r][c8]      = *(const uint4*)&Alo[(size_t)(m0 + r) * K + kt + c8];
    *(uint4*)&AsL[r + 64][c8] = *(const uint4*)&Alo[(size_t)(m0 + r + 64) * K + kt + c8];
    *(uint4*)&BsH[r][c8]      = *(const uint4*)&Bhi[(size_t)(n0 + r) * K + kt + c8];
    *(uint4*)&BsH[r + 64][c8] = *(const uint4*)&Bhi[(size_t)(n0 + r + 64) * K + kt + c8];
    *(uint4*)&BsL[r][c8]      = *(const uint4*)&Blo[(size_t)(n0 + r) * K + kt + c8];
    *(uint4*)&BsL[r + 64][c8] = *(const uint4*)&Blo[(size_t)(n0 + r + 64) * K + kt + c8];
    __syncthreads();
    f16x8 ah[4], al[4], bh2[4], bl[4];
#pragma unroll
    for (int i = 0; i < 4; i++) {
      ah[i] = *(const f16x8*)&AsH[wm + i * 16 + lc][quad * 8];
      al[i] = *(const f16x8*)&AsL[wm + i * 16 + lc][quad * 8];
    }
#pragma unroll
    for (int j = 0; j < 4; j++) {
      bh2[j] = *(const f16x8*)&BsH[wn + j * 16 + lc][quad * 8];
      bl[j]  = *(const f16x8*)&BsL[wn + j * 16 + lc][quad * 8];
    }
#pragma unroll
    for (int i = 0; i < 4; i++)
#pragma unroll
      for (int j = 0; j < 4; j++) {
        acc[i][j] = MFMA32(ah[i], bh2[j], acc[i][j]);
        acc[i][j] = MFMA32(al[i], bh2[j], acc[i][j]);
        acc[i][j] = MFMA32(ah[i], bl[j], acc[i][j]);
      }
  }
#pragma unroll
  for (int i = 0; i < 4; i++)
#pragma unroll
    for (int j = 0; j < 4; j++)
#pragma unroll
      for (int rr = 0; rr < 4; rr++) {
        int row = m0 + wm + i * 16 + quad * 4 + rr;
        int col = n0 + wn + j * 16 + lc;
        float x = acc[i][j][rr];
        f16 h = (f16)x;
        ChHi[(size_t)row * 3072 + col] = h;
        ChLo[(size_t)row * 1536 + col] = (f16)(x - (float)h);
      }
}

// ---------------------------------------------------------------------------
// 4b) Plain f16 GEMM  C[M][N] = A[M][K] @ Bw[N][K]^T, fp32 acc.
//     OUTF16=1 -> Ch f16; else Cf fp32.
// ---------------------------------------------------------------------------
template <int OUTF16>
__global__ __launch_bounds__(256) void gemm_plain(
    const f16* __restrict__ A, const f16* __restrict__ Bw,
    f16* __restrict__ Ch, float* __restrict__ Cf, int K, int ldc) {
  __shared__ __attribute__((aligned(16))) f16 As[128][40];
  __shared__ __attribute__((aligned(16))) f16 Bs[128][40];
  const int t = threadIdx.x;
  const int lane = t & 63, wave = t >> 6;
  const int lc = lane & 15, quad = lane >> 4;
  const int wm = (wave >> 1) * 64, wn = (wave & 1) * 64;
  const int m0 = blockIdx.y * 128, n0 = blockIdx.x * 128;
  const int r = t >> 2, c8 = (t & 3) * 8;
  floatx4 acc[4][4] = {};
  for (int kt = 0; kt < K; kt += 32) {
    __syncthreads();
    *(uint4*)&As[r][c8]      = *(const uint4*)&A[(size_t)(m0 + r) * K + kt + c8];
    *(uint4*)&As[r + 64][c8] = *(const uint4*)&A[(size_t)(m0 + r + 64) * K + kt + c8];
    *(uint4*)&Bs[r][c8]      = *(const uint4*)&Bw[(size_t)(n0 + r) * K + kt + c8];
    *(uint4*)&Bs[r + 64][c8] = *(const uint4*)&Bw[(size_t)(n0 + r + 64) * K + kt + c8];
    __syncthreads();
    f16x8 af[4], bf[4];
#pragma unroll
    for (int i = 0; i < 4; i++) af[i] = *(const f16x8*)&As[wm + i * 16 + lc][quad * 8];
#pragma unroll
    for (int j = 0; j < 4; j++) bf[j] = *(const f16x8*)&Bs[wn + j * 16 + lc][quad * 8];
#pragma unroll
    for (int i = 0; i < 4; i++)
#pragma unroll
      for (int j = 0; j < 4; j++) acc[i][j] = MFMA32(af[i], bf[j], acc[i][j]);
  }
#pragma unroll
  for (int i = 0; i < 4; i++)
#pragma unroll
    for (int j = 0; j < 4; j++)
#pragma unroll
      for (int rr = 0; rr < 4; rr++) {
        int row = m0 + wm + i * 16 + quad * 4 + rr;
        int col = n0 + wn + j * 16 + lc;
        if (OUTF16) Ch[(size_t)row * ldc + col] = (f16)acc[i][j][rr];
        else        Cf[(size_t)row * ldc + col] = acc[i][j][rr];
      }
}

// ---------------------------------------------------------------------------
// 5) Chunk pre-pass (block per (b,h,chunk)).  k,v from hi+lo; q hi only.
//    Outputs: -w, kT, u as hi/lo f16 pairs; attn fp32.
//    NOTE: u = T @ (v*beta) uses Tt (NOT Tb) — Tb would double-count beta.
// ---------------------------------------------------------------------------
__global__ __launch_bounds__(256) void prepass_kernel(
    const f16* __restrict__ qkvgHi, const f16* __restrict__ kvLo,
    const float* __restrict__ betaf,
    f16* __restrict__ wHi, f16* __restrict__ wLo,
    f16* __restrict__ kTHi, f16* __restrict__ kTLo,
    f16* __restrict__ uHi, f16* __restrict__ uLo,
    float* __restrict__ attno) {
  int bid = blockIdx.x;          // 16*128
  int bh = bid >> 7, n = bid & 127;
  int b = bh >> 2, h = bh & 3;
  int t = threadIdx.x;

  __shared__ __attribute__((aligned(16))) float kc[16][132];
  __shared__ __attribute__((aligned(16))) float qc[16][132];
  __shared__ __attribute__((aligned(16))) float vb[16][260];
  __shared__ float Mm[16][16];
  __shared__ float Tt[16][16];
  __shared__ float Tb[16][16];
  __shared__ float part[16][16];
  __shared__ float betas[16];
  __shared__ float nrm[16];

  const size_t rowbase = (size_t)(b * 2048 + n * 16);
  {
    int i = t >> 4, o8 = (t & 15) * 8;
    size_t oh = (rowbase + i) * 3072;
    size_t ol = (rowbase + i) * 1536;
#pragma unroll
    for (int j = 0; j < 8; j++)
      kc[i][o8 + j] = (float)qkvgHi[oh + h * 128 + o8 + j] +
                      (float)kvLo[ol + h * 128 + o8 + j];
#pragma unroll
    for (int j = 0; j < 8; j++)
      qc[i][o8 + j] = (float)qkvgHi[oh + 1536 + h * 128 + o8 + j];
  }
  if (t < 16) betas[t] = betaf[(rowbase + t) * 4 + h];
  __syncthreads();
  {
    int i = t >> 4, sg = t & 15;
    float s = 0.f;
#pragma unroll
    for (int j = 0; j < 8; j++) { float v = kc[i][sg * 8 + j]; s += v * v; }
    part[i][sg] = s;
  }
  __syncthreads();
  if (t < 16) {
    float s = 0.f;
#pragma unroll
    for (int j = 0; j < 16; j++) s += part[t][j];
    nrm[t] = rsqrtf(s + 1e-12f);
  }
  __syncthreads();
  {
    int i = t >> 4, o8 = (t & 15) * 8;
    float sc = nrm[i];
#pragma unroll
    for (int j = 0; j < 8; j++) kc[i][o8 + j] *= sc;
  }
  __syncthreads();
  { // kT: normalized k transposed [d][token], hi/lo
    int d = t & 127, ih = t >> 7;
    f16 thi[8] __attribute__((aligned(16)));
    f16 tlo[8] __attribute__((aligned(16)));
#pragma unroll
    for (int j = 0; j < 8; j++) {
      float x = kc[ih * 8 + j][d];
      f16 hh = (f16)x;
      thi[j] = hh;
      tlo[j] = (f16)(x - (float)hh);
    }
    size_t base = ((size_t)bh * 128 + n) * 2048 + d * 16 + ih * 8;
    *(uint4*)&kTHi[base] = *(const uint4*)thi;
    *(uint4*)&kTLo[base] = *(const uint4*)tlo;
  }
  { // M = I + beta_i * (k_i . k_j) strictly-lower
    int i = t >> 4, j = t & 15;
    float s = 0.f;
    for (int x = 0; x < 128; x += 4)
      s += kc[i][x] * kc[j][x] + kc[i][x + 1] * kc[j][x + 1] +
           kc[i][x + 2] * kc[j][x + 2] + kc[i][x + 3] * kc[j][x + 3];
    Mm[i][j] = (i == j ? 1.f : 0.f) + ((j < i) ? betas[i] * s : 0.f);
  }
  __syncthreads();
  if (t < 16) { // forward substitution, column t of T = M^-1 (unit lower)
    int j = t;
    float Tc[16];
#pragma unroll
    for (int i = 0; i < 16; i++) Tc[i] = 0.f;
    Tc[j] = 1.f;
    for (int i = j + 1; i < 16; i++) {
      float s = 0.f;
      for (int k2 = j; k2 < i; k2++) s += Mm[i][k2] * Tc[k2];
      Tc[i] = -s;
    }
    for (int i = 0; i < 16; i++) Tt[i][j] = Tc[i];
  }
  __syncthreads();
  { int i = t >> 4, m = t & 15; Tb[i][m] = Tt[i][m] * betas[m]; }
  { // vb = v * beta  (v = hi+lo)
    int m = t >> 4, c16 = (t & 15) * 16;
    size_t oh = (rowbase + m) * 3072 + 512 + h * 256 + c16;
    size_t ol = (rowbase + m) * 1536 + 512 + h * 256 + c16;
    float bm = betas[m];
#pragma unroll
    for (int j = 0; j < 16; j++)
      vb[m][c16 + j] = bm * ((float)qkvgHi[oh + j] + (float)kvLo[ol + j]);
  }
  __syncthreads();
  { // -w = -(T @ kb) = -(Tb @ k_norm), hi/lo   (Tb = T*beta, kc has no beta)
    int i = t >> 4, dg = t & 15;
    f16 thi[8] __attribute__((aligned(16)));
    f16 tlo[8] __attribute__((aligned(16)));
#pragma unroll
    for (int dd = 0; dd < 8; dd++) {
      int d = dg * 8 + dd;
      float s = 0.f;
#pragma unroll
      for (int m = 0; m < 16; m++) s += Tb[i][m] * kc[m][d];
      s = -s;
      f16 hh = (f16)s;
      thi[dd] = hh;
      tlo[dd] = (f16)(s - (float)hh);
    }
    size_t base = ((size_t)bh * 128 + n) * 2048 + i * 128 + dg * 8;
    *(uint4*)&wHi[base] = *(const uint4*)thi;
    *(uint4*)&wLo[base] = *(const uint4*)tlo;
  }
  { // u = T @ (v*beta) = Tt @ vb  (vb already has beta — do NOT use Tb!)
    int i = t >> 4, vg = t & 15;
    f16 thi[16] __attribute__((aligned(16)));
    f16 tlo[16] __attribute__((aligned(16)));
#pragma unroll
    for (int vv = 0; vv < 16; vv++) {
      int v = vg * 16 + vv;
      float s = 0.f;
#pragma unroll
      for (int m = 0; m < 16; m++) s += Tt[i][m] * vb[m][v];
      f16 hh = (f16)s;
      thi[vv] = hh;
      tlo[vv] = (f16)(s - (float)hh);
    }
    size_t base = ((size_t)bh * 128 + n) * 4096 + i * 256 + vg * 16;
    ((uint4*)&uHi[base])[0] = ((const uint4*)thi)[0];
    ((uint4*)&uHi[base])[1] = ((const uint4*)thi)[1];
    ((uint4*)&uLo[base])[0] = ((const uint4*)tlo)[0];
    ((uint4*)&uLo[base])[1] = ((const uint4*)tlo)[1];
  }
  { // attn = qscale * (q . k_norm), causal inclusive, fp32
    int i = t >> 4, j = t & 15;
    float s = 0.f;
    for (int x = 0; x < 128; x++) s += qc[i][x] * kc[j][x];
    attno[((size_t)bh * 128 + n) * 256 + i * 16 + j] = (j <= i) ? QSCALE * s : 0.f;
  }
}

// ---------------------------------------------------------------------------
// 6) Delta-rule scan, hi/lo compensated (~fp32).  One wave/block;
//    block = (b,h,v-slice of 16).  S fp32 in accumulators.
//    o output split: b<3 -> o1 (+b*2048*1024), b==3 -> o2.
// ---------------------------------------------------------------------------
__global__ __launch_bounds__(64) void scan_kernel(
    const f16* __restrict__ qkvgHi,
    const f16* __restrict__ wHi, const f16* __restrict__ wLo,
    const f16* __restrict__ kTHi, const f16* __restrict__ kTLo,
    const float* __restrict__ attn,
    const f16* __restrict__ uHi, const f16* __restrict__ uLo,
    float* __restrict__ o1, float* __restrict__ o2) {
  const int bid = blockIdx.x;      // 256 = 16 bh * 16 slices
  const int s = bid & 15, bh = bid >> 4;
  const int b = bh >> 2, h = bh & 3;
  const int v0 = s * 16;
  const int lane = threadIdx.x;
  const int lc = lane & 15, quad = lane >> 4;
  const int qh = quad & 1;         // token half (0: tokens 0-7, 1: 8-15)

  __shared__ __attribute__((aligned(16))) f16 wH[16][136];
  __shared__ __attribute__((aligned(16))) f16 wL[16][136];
  __shared__ __attribute__((aligned(16))) f16 qH[16][136];
  __shared__ __attribute__((aligned(16))) f16 kTH[128 * 16];
  __shared__ __attribute__((aligned(16))) f16 kTL[128 * 16];
  __shared__ __attribute__((aligned(16))) float attn_lds[256];
  __shared__ __attribute__((aligned(16))) f16 S_hi[16][136];   // [v_local][d]
  __shared__ __attribute__((aligned(16))) f16 S_lo[16][136];
  __shared__ __attribute__((aligned(16))) float u_xch[16][17]; // [token][v_local]

  floatx4 accS[8] = {};   // S[dt*16 + quad*4 + r][v0 + lc], fp32

  const size_t cb = (size_t)bh * 128;
  const size_t lbase = (size_t)b * 2048;
  float* ob = (b < 3) ? (o1 + (size_t)b * 2048 * 1024) : o2;
  const f16* qb = qkvgHi + 1536 + h * 128;

  for (int n = 0; n < NCHUNK; n++) {
    // dump hi/lo fp16 split of S
#pragma unroll
    for (int dt = 0; dt < 8; dt++) {
      f16x4 hi4, lo4;
#pragma unroll
      for (int r = 0; r < 4; r++) {
        float x = accS[dt][r];
        f16 hh = (f16)x;
        hi4[r] = hh;
        lo4[r] = (f16)(x - (float)hh);
      }
      *(f16x4*)&S_hi[lc][dt * 16 + quad * 4] = hi4;
      *(f16x4*)&S_lo[lc][dt * 16 + quad * 4] = lo4;
    }
    // stage chunk data
    const size_t coff = (cb + n) * 2048;
    const float* ac = attn + (cb + n) * 256;
    const f16* uhc = uHi + (cb + n) * 4096;
    const f16* ulc = uLo + (cb + n) * 4096;
#pragma unroll
    for (int p = 0; p < 4; p++) {
      int cid = lane + 64 * p;
      int row = cid >> 4, o8 = (cid & 15) * 8;
      *(uint4*)&wH[row][o8] = *(const uint4*)(wHi + coff + cid * 8);
      *(uint4*)&wL[row][o8] = *(const uint4*)(wLo + coff + cid * 8);
      *(uint4*)&qH[row][o8] =
          *(const uint4*)(qb + (lbase + n * 16 + row) * 3072 + o8);
      *(uint4*)(kTH + cid * 8) = *(const uint4*)(kTHi + coff + cid * 8);
      *(uint4*)(kTL + cid * 8) = *(const uint4*)(kTLo + coff + cid * 8);
    }
    *(uint4*)(attn_lds + lane * 4) = *(const uint4*)(ac + lane * 4);
    floatx4 acc_u;
#pragma unroll
    for (int r = 0; r < 4; r++) {
      int idx = (quad * 4 + r) * 256 + v0 + lc;
      acc_u[r] = (float)uhc[idx] + (float)ulc[idx];
    }
    __syncthreads();

    f16x8 wah[4], wal[4], qah[4], sh[4], sl[4];
#pragma unroll
    for (int ks = 0; ks < 4; ks++) {
      sh[ks] = *(const f16x8*)&S_hi[lc][ks * 32 + quad * 8];
      sl[ks] = *(const f16x8*)&S_lo[lc][ks * 32 + quad * 8];
      wah[ks] = *(const f16x8*)&wH[lc][ks * 32 + quad * 8];
      wal[ks] = *(const f16x8*)&wL[lc][ks * 32 + quad * 8];
      qah[ks] = *(const f16x8*)&qH[lc][ks * 32 + quad * 8];
    }
    // u_adj = u + (-w) @ S   (whi*Shi + whi*Slo + wlo*Shi)
#pragma unroll
    for (int ks = 0; ks < 4; ks++) acc_u = MFMA32(wah[ks], sh[ks], acc_u);
#pragma unroll
    for (int ks = 0; ks < 4; ks++) acc_u = MFMA32(wah[ks], sl[ks], acc_u);
#pragma unroll
    for (int ks = 0; ks < 4; ks++) acc_u = MFMA32(wal[ks], sh[ks], acc_u);
    // o_part = q @ S (q f16 hi; terminal term)
    floatx4 acc_o = {0.f, 0.f, 0.f, 0.f};
#pragma unroll
    for (int ks = 0; ks < 4; ks++) acc_o = MFMA32(qah[ks], sh[ks], acc_o);
#pragma unroll
    for (int ks = 0; ks < 4; ks++) acc_o = MFMA32(qah[ks], sl[ks], acc_o);

    // exchange u_adj (C-layout rows quad*4+r) -> B-layout rows qh*8+j, fp32
#pragma unroll
    for (int r = 0; r < 4; r++) u_xch[quad * 4 + r][lc] = acc_u[r];
    __syncthreads();
    f16x8 ubf, aah, aal;  // B: k<16 = u_hi tokens, k>=16 = u_lo tokens
#pragma unroll
    for (int j = 0; j < 8; j++) {
      float x = u_xch[qh * 8 + j][lc];
      f16 hh = (f16)x;
      ubf[j] = (quad < 2) ? hh : (f16)(x - (float)hh);
      float a = attn_lds[lc * 16 + qh * 8 + j];
      f16 ahh = (f16)a;
      aah[j] = ahh;
      aal[j] = (f16)(a - (float)ahh);
    }
#pragma unroll
    for (int r = 0; r < 4; r++) acc_o[r] *= QSCALE;
    acc_o = MFMA32(aah, ubf, acc_o);
    acc_o = MFMA32(aal, ubf, acc_o);
#pragma unroll
    for (int r = 0; r < 4; r++)
      ob[((size_t)((n * 16 + quad * 4 + r) * 4 + h)) * 256 + v0 + lc] = acc_o[r];
    // S += k^T @ u_adj   ((khi+klo)*(uhi+ulo))
#pragma unroll
    for (int dt = 0; dt < 8; dt++) {
      f16x8 kah = *(const f16x8*)&kTH[(dt * 16 + lc) * 16 + qh * 8];
      f16x8 kal = *(const f16x8*)&kTL[(dt * 16 + lc) * 16 + qh * 8];
      accS[dt] = MFMA32(kah, ubf, accS[dt]);
      accS[dt] = MFMA32(kal, ubf, accS[dt]);
    }
    __syncthreads();
  }
}

// ---------------------------------------------------------------------------
// 7) Gated RMSNorm -> on f16 (hi only; terminal factor)
// ---------------------------------------------------------------------------
__global__ __launch_bounds__(256) void gate_kernel(
    const float* __restrict__ o1, const float* __restrict__ o2,
    const f16* __restrict__ qkvgHi, const float* __restrict__ norm_w,
    f16* __restrict__ onh) {
  int h = threadIdx.x >> 6, lane = threadIdx.x & 63;
  int r = blockIdx.x;              // b*L + l
  int rh = r * 4 + h;
  const float* orow = (rh < 24576) ? (o1 + (size_t)rh * 256)
                                   : (o2 + (size_t)(rh - 24576) * 256);
  int v = lane * 4;
  floatx4 ov = *(const floatx4*)&orow[v];
  float ss = ov[0] * ov[0] + ov[1] * ov[1] + ov[2] * ov[2] + ov[3] * ov[3];
  for (int m = 32; m > 0; m >>= 1) ss += __shfl_xor(ss, m);
  float rms = rsqrtf(ss * (1.0f / 256.0f) + 1e-5f);
  size_t goff = (size_t)r * 3072 + 2048 + h * 256 + v;
  floatx4 nw = *(const floatx4*)&norm_w[v];
  f16 outv[4] __attribute__((aligned(8)));
#pragma unroll
  for (int q2 = 0; q2 < 4; q2++) {
    float g = (float)qkvgHi[goff + q2];
    outv[q2] = (f16)(ov[q2] * rms * nw[q2] * (g * sigmoidf_(g)));
  }
  *(uint2*)&onh[(size_t)r * 1024 + h * 256 + v] = *(const uint2*)outv;
}

// ---------------------------------------------------------------------------
extern "C" void kernel_launch(void* const* d_in, const int* in_sizes, int n_in,
                              void* d_out, int out_size, void* d_ws, size_t ws_size,
                              hipStream_t stream) {
  (void)in_sizes; (void)n_in; (void)out_size; (void)ws_size;
  const float* hs     = (const float*)d_in[0];
  const float* conv_w = (const float*)d_in[1];
  const float* Wq     = (const float*)d_in[2];
  const float* Wk     = (const float*)d_in[3];
  const float* Wv     = (const float*)d_in[4];
  const float* Wb     = (const float*)d_in[5];
  const float* Wg     = (const float*)d_in[6];
  const float* Wo     = (const float*)d_in[7];
  const float* norm_w = (const float*)d_in[8];
  float* out = (float*)d_out;   // fp32 output (confirmed by R5 falsification)

  char* ws = (char*)d_ws;
  // Layout (bytes). Aliases noted; stream order guarantees safety.
  f16*   x_hi    = (f16*)(ws + 0);            // 16,777,216  -> uHi after GEMM1
  f16*   x_lo    = (f16*)(ws + 16777216);     // 16,777,216  -> uLo after GEMM1
  f16*   uHi     = (f16*)(ws + 0);
  f16*   uLo     = (f16*)(ws + 16777216);
  f16*   WcatHi  = (f16*)(ws + 33554432);     //  6,291,456  -> o_f region2 after
  float* o2f     = (float*)(ws + 33554432);   //  8,388,608  (rows 24576..32767)
  f16*   WcatLo  = (f16*)(ws + 39845888);     //  3,145,728  (kv rows only)
  f16*   WoHi    = (f16*)(ws + 42991616);     //  2,097,152  (live to end)
  float* betaf   = (float*)(ws + 45088768);   //    131,072
  f16*   qkvgHi  = (f16*)(ws + 45219840);     // 50,331,648  [8192][3072]
  f16*   kvLo    = (f16*)(ws + 95551488);     // 25,165,824  [8192][1536] -> o_f region1
  float* o1f     = (float*)(ws + 95551488);   // 25,165,824  (rows 0..24575)
  f16*   wHi     = (f16*)(ws + 120717312);    //  8,388,608  -> on_h after scan
  f16*   on_h    = (f16*)(ws + 120717312);    // 16,777,216
  f16*   wLo     = (f16*)(ws + 129105920);    //  8,388,608
  f16*   kTHi    = (f16*)(ws + 137494528);    //  8,388,608
  f16*   kTLo    = (f16*)(ws + 145883136);    //  8,388,608
  float* attnf   = (float*)(ws + 154271744);  //  2,097,152  -> total 156,368,896

  wconv_kernel<<<2048, 256, 0, stream>>>(Wq, Wk, Wv, Wg, Wo, WcatHi, WcatLo, WoHi);
  conv_kernel<<<ROWS, 256, 0, stream>>>(hs, conv_w, x_hi, x_lo);
  beta_kernel<<<ROWS, 256, 0, stream>>>(x_hi, x_lo, Wb, betaf);
  // k,v columns [0,1536): hi/lo GEMM
  gemm_hilo_kv<<<dim3(12, 64), 256, 0, stream>>>(
      x_hi, x_lo, WcatHi, WcatLo, qkvgHi, kvLo, 1024);
  // q,g columns [1536,3072): plain GEMM into qkvgHi+1536
  gemm_plain<1><<<dim3(12, 64), 256, 0, stream>>>(
      x_hi, WcatHi + (size_t)1536 * 1024, qkvgHi + 1536, nullptr, 1024, 3072);
  prepass_kernel<<<16 * NCHUNK, 256, 0, stream>>>(
      qkvgHi, kvLo, betaf, wHi, wLo, kTHi, kTLo, uHi, uLo, attnf);
  scan_kernel<<<256, 64, 0, stream>>>(
      qkvgHi, wHi, wLo, kTHi, kTLo, attnf, uHi, uLo, o1f, o2f);
  gate_kernel<<<ROWS, 256, 0, stream>>>(o1f, o2f, qkvgHi, norm_w, on_h);
  // Final GEMM: fp32 output into d_out
  gemm_plain<0><<<dim3(8, 64), 256, 0, stream>>>(
      on_h, WoHi, nullptr, out, 1024, 1024);
}

// Round 7
// 713.707 us; speedup vs baseline: 1.8660x; 1.8660x over previous
//
#include <hip/hip_runtime.h>
#include <cstdint>
#include <cstddef>

typedef _Float16 f16;
typedef _Float16 f16x4 __attribute__((ext_vector_type(4)));
typedef _Float16 f16x8 __attribute__((ext_vector_type(8)));
typedef float floatx4 __attribute__((ext_vector_type(4)));

#define MFMA32(a,b,c) __builtin_amdgcn_mfma_f32_16x16x32_f16((a),(b),(c),0,0,0)

#define ROWS 8192            // B*L
#define NCHUNK 128           // L/CS
// qkvgHi column order: k [0,512) | v [512,1536) | q [1536,2048) | g [2048,3072)
static constexpr float QSCALE = 0.08838834764831845f; // 128^-0.5

static __device__ __forceinline__ float sigmoidf_(float x) { return 1.0f / (1.0f + expf(-x)); }

static __device__ __forceinline__ uint32_t pack2(f16 a, f16 b) {
  union { f16 h[2]; uint32_t u; } v; v.h[0] = a; v.h[1] = b; return v.u;
}

// ---------------------------------------------------------------------------
// 1) Weights -> f16. Wcat rows: [0,512)=Wk [512,1536)=Wv [1536,2048)=Wq
//    [2048,3072)=Wg. hi all; lo only k,v rows. Wo -> hi only.
// ---------------------------------------------------------------------------
__global__ __launch_bounds__(256) void wconv_kernel(
    const float* __restrict__ Wq, const float* __restrict__ Wk,
    const float* __restrict__ Wv, const float* __restrict__ Wg,
    const float* __restrict__ Wo,
    f16* __restrict__ WcatHi, f16* __restrict__ WcatLoKV, f16* __restrict__ WoHi) {
  int tid = blockIdx.x * 256 + threadIdx.x;
  int e8 = tid * 8;
  if (e8 < 3145728) {
    int row = e8 >> 10, col = e8 & 1023;
    const float* src;
    if (row < 512)       src = Wk + (size_t)row * 1024 + col;
    else if (row < 1536) src = Wv + (size_t)(row - 512) * 1024 + col;
    else if (row < 2048) src = Wq + (size_t)(row - 1536) * 1024 + col;
    else                 src = Wg + (size_t)(row - 2048) * 1024 + col;
    f16 thi[8] __attribute__((aligned(16)));
    f16 tlo[8] __attribute__((aligned(16)));
#pragma unroll
    for (int j = 0; j < 8; j++) {
      float x = src[j];
      f16 h = (f16)x;
      thi[j] = h;
      tlo[j] = (f16)(x - (float)h);
    }
    *(uint4*)&WcatHi[e8] = *(const uint4*)thi;
    if (row < 1536) *(uint4*)&WcatLoKV[e8] = *(const uint4*)tlo;
  } else {
    int idx = e8 - 3145728;
    f16 t[8] __attribute__((aligned(16)));
#pragma unroll
    for (int j = 0; j < 8; j++) t[j] = (f16)Wo[idx + j];
    *(uint4*)&WoHi[idx] = *(const uint4*)t;
  }
}

// ---------------------------------------------------------------------------
// 2) Causal depthwise conv1d (K=4) + SiLU -> x hi/lo
// ---------------------------------------------------------------------------
__global__ __launch_bounds__(256) void conv_kernel(
    const float* __restrict__ hs, const float* __restrict__ cw,
    f16* __restrict__ xhi, f16* __restrict__ xlo) {
  int row = blockIdx.x;
  int b = row >> 11, l = row & 2047;
  int d = threadIdx.x * 4;
  floatx4 w0 = *(const floatx4*)&cw[(d + 0) * 4];
  floatx4 w1 = *(const floatx4*)&cw[(d + 1) * 4];
  floatx4 w2 = *(const floatx4*)&cw[(d + 2) * 4];
  floatx4 w3 = *(const floatx4*)&cw[(d + 3) * 4];
  floatx4 acc = {0.f, 0.f, 0.f, 0.f};
#pragma unroll
  for (int j = 0; j < 4; j++) {
    int ls = l - 3 + j;
    if (ls < 0) continue;
    floatx4 hv = *(const floatx4*)&hs[(size_t)(b * 2048 + ls) * 1024 + d];
    acc[0] += hv[0] * w0[j];
    acc[1] += hv[1] * w1[j];
    acc[2] += hv[2] * w2[j];
    acc[3] += hv[3] * w3[j];
  }
  f16 ohi[4] __attribute__((aligned(8)));
  f16 olo[4] __attribute__((aligned(8)));
#pragma unroll
  for (int q = 0; q < 4; q++) {
    float y = acc[q] * sigmoidf_(acc[q]);
    f16 h = (f16)y;
    ohi[q] = h;
    olo[q] = (f16)(y - (float)h);
  }
  *(uint2*)&xhi[(size_t)row * 1024 + d] = *(const uint2*)ohi;
  *(uint2*)&xlo[(size_t)row * 1024 + d] = *(const uint2*)olo;
}

// ---------------------------------------------------------------------------
// 3) beta[row][h] = sigmoid(x . Wb[h])
// ---------------------------------------------------------------------------
__global__ __launch_bounds__(256) void beta_kernel(
    const f16* __restrict__ xhi, const f16* __restrict__ xlo,
    const float* __restrict__ Wb, float* __restrict__ betaf) {
  int row = blockIdx.x;
  int t = threadIdx.x;
  __shared__ floatx4 red[256];
  int c = t * 4;
  float xv[4];
#pragma unroll
  for (int j = 0; j < 4; j++)
    xv[j] = (float)xhi[(size_t)row * 1024 + c + j] + (float)xlo[(size_t)row * 1024 + c + j];
  floatx4 p = {0.f, 0.f, 0.f, 0.f};
#pragma unroll
  for (int hh = 0; hh < 4; hh++) {
    const float* wr = Wb + hh * 1024 + c;
    p[hh] = xv[0] * wr[0] + xv[1] * wr[1] + xv[2] * wr[2] + xv[3] * wr[3];
  }
  red[t] = p;
  __syncthreads();
  for (int s = 128; s > 0; s >>= 1) {
    if (t < s) red[t] += red[t + s];
    __syncthreads();
  }
  if (t < 4) betaf[(size_t)row * 4 + t] = sigmoidf_(red[0][t]);
}

// ---------------------------------------------------------------------------
// 4a) hi/lo GEMM for k,v cols (3 MFMAs/tile).
// ---------------------------------------------------------------------------
__global__ __launch_bounds__(256) void gemm_hilo_kv(
    const f16* __restrict__ Ahi, const f16* __restrict__ Alo,
    const f16* __restrict__ Bhi, const f16* __restrict__ Blo,
    f16* __restrict__ ChHi, f16* __restrict__ ChLo, int K) {
  __shared__ __attribute__((aligned(16))) f16 AsH[128][40];
  __shared__ __attribute__((aligned(16))) f16 AsL[128][40];
  __shared__ __attribute__((aligned(16))) f16 BsH[128][40];
  __shared__ __attribute__((aligned(16))) f16 BsL[128][40];
  const int t = threadIdx.x;
  const int lane = t & 63, wave = t >> 6;
  const int lc = lane & 15, quad = lane >> 4;
  const int wm = (wave >> 1) * 64, wn = (wave & 1) * 64;
  const int m0 = blockIdx.y * 128, n0 = blockIdx.x * 128;
  const int r = t >> 2, c8 = (t & 3) * 8;
  floatx4 acc[4][4] = {};
  for (int kt = 0; kt < K; kt += 32) {
    __syncthreads();
    *(uint4*)&AsH[r][c8]      = *(const uint4*)&Ahi[(size_t)(m0 + r) * K + kt + c8];
    *(uint4*)&AsH[r + 64][c8] = *(const uint4*)&Ahi[(size_t)(m0 + r + 64) * K + kt + c8];
    *(uint4*)&AsL[r][c8]      = *(const uint4*)&Alo[(size_t)(m0 + r) * K + kt + c8];
    *(uint4*)&AsL[r + 64][c8] = *(const uint4*)&Alo[(size_t)(m0 + r + 64) * K + kt + c8];
    *(uint4*)&BsH[r][c8]      = *(const uint4*)&Bhi[(size_t)(n0 + r) * K + kt + c8];
    *(uint4*)&BsH[r + 64][c8] = *(const uint4*)&Bhi[(size_t)(n0 + r + 64) * K + kt + c8];
    *(uint4*)&BsL[r][c8]      = *(const uint4*)&Blo[(size_t)(n0 + r) * K + kt + c8];
    *(uint4*)&BsL[r + 64][c8] = *(const uint4*)&Blo[(size_t)(n0 + r + 64) * K + kt + c8];
    __syncthreads();
    f16x8 ah[4], al[4], bh2[4], bl[4];
#pragma unroll
    for (int i = 0; i < 4; i++) {
      ah[i] = *(const f16x8*)&AsH[wm + i * 16 + lc][quad * 8];
      al[i] = *(const f16x8*)&AsL[wm + i * 16 + lc][quad * 8];
    }
#pragma unroll
    for (int j = 0; j < 4; j++) {
      bh2[j] = *(const f16x8*)&BsH[wn + j * 16 + lc][quad * 8];
      bl[j]  = *(const f16x8*)&BsL[wn + j * 16 + lc][quad * 8];
    }
#pragma unroll
    for (int i = 0; i < 4; i++)
#pragma unroll
      for (int j = 0; j < 4; j++) {
        acc[i][j] = MFMA32(ah[i], bh2[j], acc[i][j]);
        acc[i][j] = MFMA32(al[i], bh2[j], acc[i][j]);
        acc[i][j] = MFMA32(ah[i], bl[j], acc[i][j]);
      }
  }
#pragma unroll
  for (int i = 0; i < 4; i++)
#pragma unroll
    for (int j = 0; j < 4; j++)
#pragma unroll
      for (int rr = 0; rr < 4; rr++) {
        int row = m0 + wm + i * 16 + quad * 4 + rr;
        int col = n0 + wn + j * 16 + lc;
        float x = acc[i][j][rr];
        f16 h = (f16)x;
        ChHi[(size_t)row * 3072 + col] = h;
        ChLo[(size_t)row * 1536 + col] = (f16)(x - (float)h);
      }
}

// ---------------------------------------------------------------------------
// 4b) Plain f16 GEMM. OUTF16=1 -> f16; else fp32.
// ---------------------------------------------------------------------------
template <int OUTF16>
__global__ __launch_bounds__(256) void gemm_plain(
    const f16* __restrict__ A, const f16* __restrict__ Bw,
    f16* __restrict__ Ch, float* __restrict__ Cf, int K, int ldc) {
  __shared__ __attribute__((aligned(16))) f16 As[128][40];
  __shared__ __attribute__((aligned(16))) f16 Bs[128][40];
  const int t = threadIdx.x;
  const int lane = t & 63, wave = t >> 6;
  const int lc = lane & 15, quad = lane >> 4;
  const int wm = (wave >> 1) * 64, wn = (wave & 1) * 64;
  const int m0 = blockIdx.y * 128, n0 = blockIdx.x * 128;
  const int r = t >> 2, c8 = (t & 3) * 8;
  floatx4 acc[4][4] = {};
  for (int kt = 0; kt < K; kt += 32) {
    __syncthreads();
    *(uint4*)&As[r][c8]      = *(const uint4*)&A[(size_t)(m0 + r) * K + kt + c8];
    *(uint4*)&As[r + 64][c8] = *(const uint4*)&A[(size_t)(m0 + r + 64) * K + kt + c8];
    *(uint4*)&Bs[r][c8]      = *(const uint4*)&Bw[(size_t)(n0 + r) * K + kt + c8];
    *(uint4*)&Bs[r + 64][c8] = *(const uint4*)&Bw[(size_t)(n0 + r + 64) * K + kt + c8];
    __syncthreads();
    f16x8 af[4], bf[4];
#pragma unroll
    for (int i = 0; i < 4; i++) af[i] = *(const f16x8*)&As[wm + i * 16 + lc][quad * 8];
#pragma unroll
    for (int j = 0; j < 4; j++) bf[j] = *(const f16x8*)&Bs[wn + j * 16 + lc][quad * 8];
#pragma unroll
    for (int i = 0; i < 4; i++)
#pragma unroll
      for (int j = 0; j < 4; j++) acc[i][j] = MFMA32(af[i], bf[j], acc[i][j]);
  }
#pragma unroll
  for (int i = 0; i < 4; i++)
#pragma unroll
    for (int j = 0; j < 4; j++)
#pragma unroll
      for (int rr = 0; rr < 4; rr++) {
        int row = m0 + wm + i * 16 + quad * 4 + rr;
        int col = n0 + wn + j * 16 + lc;
        if (OUTF16) Ch[(size_t)row * ldc + col] = (f16)acc[i][j][rr];
        else        Cf[(size_t)row * ldc + col] = acc[i][j][rr];
      }
}

// ---------------------------------------------------------------------------
// 5) Chunk pre-pass.  u now SLICE-MAJOR: [s][bh][n][row16][16] (hi/lo).
//    u = Tt @ vb (vb carries beta — do NOT use Tb).
// ---------------------------------------------------------------------------
__global__ __launch_bounds__(256) void prepass_kernel(
    const f16* __restrict__ qkvgHi, const f16* __restrict__ kvLo,
    const float* __restrict__ betaf,
    f16* __restrict__ wHi, f16* __restrict__ wLo,
    f16* __restrict__ kTHi, f16* __restrict__ kTLo,
    f16* __restrict__ uHi, f16* __restrict__ uLo,
    float* __restrict__ attno) {
  int bid = blockIdx.x;          // 16*128
  int bh = bid >> 7, n = bid & 127;
  int b = bh >> 2, h = bh & 3;
  int t = threadIdx.x;

  __shared__ __attribute__((aligned(16))) float kc[16][132];
  __shared__ __attribute__((aligned(16))) float qc[16][132];
  __shared__ __attribute__((aligned(16))) float vb[16][260];
  __shared__ float Mm[16][16];
  __shared__ float Tt[16][16];
  __shared__ float Tb[16][16];
  __shared__ float part[16][16];
  __shared__ float betas[16];
  __shared__ float nrm[16];

  const size_t rowbase = (size_t)(b * 2048 + n * 16);
  {
    int i = t >> 4, o8 = (t & 15) * 8;
    size_t oh = (rowbase + i) * 3072;
    size_t ol = (rowbase + i) * 1536;
#pragma unroll
    for (int j = 0; j < 8; j++)
      kc[i][o8 + j] = (float)qkvgHi[oh + h * 128 + o8 + j] +
                      (float)kvLo[ol + h * 128 + o8 + j];
#pragma unroll
    for (int j = 0; j < 8; j++)
      qc[i][o8 + j] = (float)qkvgHi[oh + 1536 + h * 128 + o8 + j];
  }
  if (t < 16) betas[t] = betaf[(rowbase + t) * 4 + h];
  __syncthreads();
  {
    int i = t >> 4, sg = t & 15;
    float s = 0.f;
#pragma unroll
    for (int j = 0; j < 8; j++) { float v = kc[i][sg * 8 + j]; s += v * v; }
    part[i][sg] = s;
  }
  __syncthreads();
  if (t < 16) {
    float s = 0.f;
#pragma unroll
    for (int j = 0; j < 16; j++) s += part[t][j];
    nrm[t] = rsqrtf(s + 1e-12f);
  }
  __syncthreads();
  {
    int i = t >> 4, o8 = (t & 15) * 8;
    float sc = nrm[i];
#pragma unroll
    for (int j = 0; j < 8; j++) kc[i][o8 + j] *= sc;
  }
  __syncthreads();
  { // kT: normalized k transposed [d][token], hi/lo
    int d = t & 127, ih = t >> 7;
    f16 thi[8] __attribute__((aligned(16)));
    f16 tlo[8] __attribute__((aligned(16)));
#pragma unroll
    for (int j = 0; j < 8; j++) {
      float x = kc[ih * 8 + j][d];
      f16 hh = (f16)x;
      thi[j] = hh;
      tlo[j] = (f16)(x - (float)hh);
    }
    size_t base = ((size_t)bh * 128 + n) * 2048 + d * 16 + ih * 8;
    *(uint4*)&kTHi[base] = *(const uint4*)thi;
    *(uint4*)&kTLo[base] = *(const uint4*)tlo;
  }
  { // M = I + beta_i * (k_i . k_j) strictly-lower
    int i = t >> 4, j = t & 15;
    float s = 0.f;
    for (int x = 0; x < 128; x += 4)
      s += kc[i][x] * kc[j][x] + kc[i][x + 1] * kc[j][x + 1] +
           kc[i][x + 2] * kc[j][x + 2] + kc[i][x + 3] * kc[j][x + 3];
    Mm[i][j] = (i == j ? 1.f : 0.f) + ((j < i) ? betas[i] * s : 0.f);
  }
  __syncthreads();
  if (t < 16) { // forward substitution, column t of T = M^-1
    int j = t;
    float Tc[16];
#pragma unroll
    for (int i = 0; i < 16; i++) Tc[i] = 0.f;
    Tc[j] = 1.f;
    for (int i = j + 1; i < 16; i++) {
      float s = 0.f;
      for (int k2 = j; k2 < i; k2++) s += Mm[i][k2] * Tc[k2];
      Tc[i] = -s;
    }
    for (int i = 0; i < 16; i++) Tt[i][j] = Tc[i];
  }
  __syncthreads();
  { int i = t >> 4, m = t & 15; Tb[i][m] = Tt[i][m] * betas[m]; }
  { // vb = v * beta
    int m = t >> 4, c16 = (t & 15) * 16;
    size_t oh = (rowbase + m) * 3072 + 512 + h * 256 + c16;
    size_t ol = (rowbase + m) * 1536 + 512 + h * 256 + c16;
    float bm = betas[m];
#pragma unroll
    for (int j = 0; j < 16; j++)
      vb[m][c16 + j] = bm * ((float)qkvgHi[oh + j] + (float)kvLo[ol + j]);
  }
  __syncthreads();
  { // -w = -(Tb @ k_norm), hi/lo
    int i = t >> 4, dg = t & 15;
    f16 thi[8] __attribute__((aligned(16)));
    f16 tlo[8] __attribute__((aligned(16)));
#pragma unroll
    for (int dd = 0; dd < 8; dd++) {
      int d = dg * 8 + dd;
      float s = 0.f;
#pragma unroll
      for (int m = 0; m < 16; m++) s += Tb[i][m] * kc[m][d];
      s = -s;
      f16 hh = (f16)s;
      thi[dd] = hh;
      tlo[dd] = (f16)(s - (float)hh);
    }
    size_t base = ((size_t)bh * 128 + n) * 2048 + i * 128 + dg * 8;
    *(uint4*)&wHi[base] = *(const uint4*)thi;
    *(uint4*)&wLo[base] = *(const uint4*)tlo;
  }
  { // u = Tt @ vb, hi/lo, SLICE-MAJOR out: [vg][bh][n][i][16]
    int i = t >> 4, vg = t & 15;
    f16 thi[16] __attribute__((aligned(16)));
    f16 tlo[16] __attribute__((aligned(16)));
#pragma unroll
    for (int vv = 0; vv < 16; vv++) {
      int v = vg * 16 + vv;
      float s = 0.f;
#pragma unroll
      for (int m = 0; m < 16; m++) s += Tt[i][m] * vb[m][v];
      f16 hh = (f16)s;
      thi[vv] = hh;
      tlo[vv] = (f16)(s - (float)hh);
    }
    size_t base = ((((size_t)vg * 16 + bh) * 128 + n) * 16 + i) * 16;
    ((uint4*)&uHi[base])[0] = ((const uint4*)thi)[0];
    ((uint4*)&uHi[base])[1] = ((const uint4*)thi)[1];
    ((uint4*)&uLo[base])[0] = ((const uint4*)tlo)[0];
    ((uint4*)&uLo[base])[1] = ((const uint4*)tlo)[1];
  }
  { // attn = qscale * (q . k_norm), causal inclusive, fp32
    int i = t >> 4, j = t & 15;
    float s = 0.f;
    for (int x = 0; x < 128; x++) s += qc[i][x] * kc[j][x];
    attno[((size_t)bh * 128 + n) * 256 + i * 16 + j] = (j <= i) ? QSCALE * s : 0.f;
  }
}

// ---------------------------------------------------------------------------
// 6) Delta-rule scan, register-prefetch software pipeline.
//    One wave/block; 256 blocks = 16 bh x 16 v-slices.  S fp32 in regs.
//    Per chunk: 1 barrier; chunk n+1 global->reg prefetch overlaps chunk n
//    compute; u_adj layout exchange via __shfl (no mid-chunk barrier).
//    o output BH-MAJOR: o[bh][l][256]; bh<12 -> o1, else o2.
// ---------------------------------------------------------------------------
__global__ __launch_bounds__(64, 1) void scan_kernel(
    const f16* __restrict__ qkvgHi,
    const f16* __restrict__ wHi, const f16* __restrict__ wLo,
    const f16* __restrict__ kTHi, const f16* __restrict__ kTLo,
    const float* __restrict__ attn,
    const f16* __restrict__ uHi, const f16* __restrict__ uLo,
    float* __restrict__ o1, float* __restrict__ o2) {
  const int bid = blockIdx.x;
  const int s = bid & 15, bh = bid >> 4;
  const int b = bh >> 2, h = bh & 3;
  const int v0 = s * 16;
  const int lane = threadIdx.x;
  const int lc = lane & 15, quad = lane >> 4;
  const int qh = quad & 1;

  __shared__ __attribute__((aligned(16))) f16 wH_lds[16][136];
  __shared__ __attribute__((aligned(16))) f16 wL_lds[16][136];
  __shared__ __attribute__((aligned(16))) f16 q_lds[16][136];
  __shared__ __attribute__((aligned(16))) f16 kTH_lds[128 * 24];
  __shared__ __attribute__((aligned(16))) f16 kTL_lds[128 * 24];
  __shared__ __attribute__((aligned(16))) float attn_lds[16][20];
  __shared__ __attribute__((aligned(16))) f16 S_hi[16][136];
  __shared__ __attribute__((aligned(16))) f16 S_lo[16][136];

  floatx4 accS[8] = {};   // S[dt*16 + quad*4 + r][v0 + lc]

  const size_t cb = (size_t)bh * 128;
  const f16* qb = qkvgHi + (size_t)b * 2048 * 3072 + 1536 + h * 128;
  const f16* ub  = uHi + ((size_t)(s * 16 + bh)) * 128 * 256;
  const f16* ubL = uLo + ((size_t)(s * 16 + bh)) * 128 * 256;
  float* ob = (bh < 12) ? (o1 + (size_t)bh * 2048 * 256)
                        : (o2 + (size_t)(bh - 12) * 2048 * 256);

  // prefetch registers (chunk n+1 while computing n)
  uint4 pw[4], pwl[4], pq[4], pkh[4], pkl[4], pa;
  f16 puh[4], pul[4];

#define ISSUE(nn) {                                                          \
    size_t coff = (cb + (size_t)(nn)) * 2048;                                \
    _Pragma("unroll")                                                        \
    for (int p = 0; p < 4; p++) {                                            \
      int cid = lane + 64 * p;                                               \
      pw[p]  = *(const uint4*)(wHi  + coff + cid * 8);                       \
      pwl[p] = *(const uint4*)(wLo  + coff + cid * 8);                       \
      pkh[p] = *(const uint4*)(kTHi + coff + cid * 8);                       \
      pkl[p] = *(const uint4*)(kTLo + coff + cid * 8);                       \
      pq[p]  = *(const uint4*)(qb + (size_t)((nn) * 16 + (cid >> 4)) * 3072  \
                               + (cid & 15) * 8);                            \
    }                                                                        \
    pa = *(const uint4*)(attn + (cb + (size_t)(nn)) * 256 + lane * 4);       \
    _Pragma("unroll")                                                        \
    for (int r = 0; r < 4; r++) {                                            \
      puh[r] = ub [(nn) * 256 + (quad * 4 + r) * 16 + lc];                   \
      pul[r] = ubL[(nn) * 256 + (quad * 4 + r) * 16 + lc];                   \
    } }

#define COMMIT() {                                                           \
    _Pragma("unroll")                                                        \
    for (int p = 0; p < 4; p++) {                                            \
      int cid = lane + 64 * p;                                               \
      int row = cid >> 4, o8 = (cid & 15) * 8;                               \
      *(uint4*)&wH_lds[row][o8] = pw[p];                                     \
      *(uint4*)&wL_lds[row][o8] = pwl[p];                                    \
      *(uint4*)&q_lds[row][o8]  = pq[p];                                     \
      int krow = cid >> 1, kh = (cid & 1) * 8;                               \
      *(uint4*)&kTH_lds[krow * 24 + kh] = pkh[p];                            \
      *(uint4*)&kTL_lds[krow * 24 + kh] = pkl[p];                            \
    }                                                                        \
    *(uint4*)&attn_lds[lane >> 2][(lane & 3) * 4] = pa; }

  ISSUE(0);
  COMMIT();

  for (int n = 0; n < NCHUNK; n++) {
    // dump hi/lo split of S to LDS (ordered vs frag reads by the barrier)
#pragma unroll
    for (int dt = 0; dt < 8; dt++) {
      f16x4 h4, l4;
#pragma unroll
      for (int r = 0; r < 4; r++) {
        float x = accS[dt][r];
        f16 hh = (f16)x;
        h4[r] = hh;
        l4[r] = (f16)(x - (float)hh);
      }
      *(f16x4*)&S_hi[lc][dt * 16 + quad * 4] = h4;
      *(f16x4*)&S_lo[lc][dt * 16 + quad * 4] = l4;
    }
    __syncthreads();

    // consume u prefetch regs BEFORE reissuing (WAR on pu regs)
    floatx4 acc_u;
#pragma unroll
    for (int r = 0; r < 4; r++) acc_u[r] = (float)puh[r] + (float)pul[r];

    if (n + 1 < NCHUNK) ISSUE(n + 1);   // overlap with compute below

    f16x8 sh[4], sl[4], wah[4], wal[4], qah[4];
#pragma unroll
    for (int ks = 0; ks < 4; ks++) {
      sh[ks]  = *(const f16x8*)&S_hi[lc][ks * 32 + quad * 8];
      sl[ks]  = *(const f16x8*)&S_lo[lc][ks * 32 + quad * 8];
      wah[ks] = *(const f16x8*)&wH_lds[lc][ks * 32 + quad * 8];
      wal[ks] = *(const f16x8*)&wL_lds[lc][ks * 32 + quad * 8];
      qah[ks] = *(const f16x8*)&q_lds[lc][ks * 32 + quad * 8];
    }
    // u_adj = u + (-w)@S : 3 parallel accumulators (depth 4)
    floatx4 a1 = {0.f, 0.f, 0.f, 0.f}, a2 = {0.f, 0.f, 0.f, 0.f};
#pragma unroll
    for (int ks = 0; ks < 4; ks++) {
      acc_u = MFMA32(wah[ks], sh[ks], acc_u);
      a1    = MFMA32(wah[ks], sl[ks], a1);
      a2    = MFMA32(wal[ks], sh[ks], a2);
    }
    acc_u = acc_u + a1 + a2;
    // o_part = q @ S (off critical path)
    floatx4 acc_o = {0.f, 0.f, 0.f, 0.f};
#pragma unroll
    for (int ks = 0; ks < 4; ks++) acc_o = MFMA32(qah[ks], sh[ks], acc_o);
#pragma unroll
    for (int ks = 0; ks < 4; ks++) acc_o = MFMA32(qah[ks], sl[ks], acc_o);

    // u_adj C-layout -> B-frag via shfl quad-permute (no barrier).
    // B row k: k<16 = token k (hi), k>=16 = token k-16 (lo).
    // dest (quad,j): token = qh*8+j; src lane = (2*qh + (j>>2))*16 + lc.
    f16x8 ubf;
    {
      f16 h0 = (f16)acc_u[0], h1 = (f16)acc_u[1];
      f16 h2 = (f16)acc_u[2], h3 = (f16)acc_u[3];
      uint32_t uh01 = pack2(h0, h1), uh23 = pack2(h2, h3);
      uint32_t ul01 = pack2((f16)(acc_u[0] - (float)h0), (f16)(acc_u[1] - (float)h1));
      uint32_t ul23 = pack2((f16)(acc_u[2] - (float)h2), (f16)(acc_u[3] - (float)h3));
      int srcA = (2 * qh) * 16 + lc;
      int srcB = srcA + 16;
      uint32_t Ah0 = __shfl((int)uh01, srcA, 64), Ah1 = __shfl((int)uh23, srcA, 64);
      uint32_t Bh0 = __shfl((int)uh01, srcB, 64), Bh1 = __shfl((int)uh23, srcB, 64);
      uint32_t Al0 = __shfl((int)ul01, srcA, 64), Al1 = __shfl((int)ul23, srcA, 64);
      uint32_t Bl0 = __shfl((int)ul01, srcB, 64), Bl1 = __shfl((int)ul23, srcB, 64);
      union { uint32_t u[4]; f16x8 v; } U;
      bool hi = (quad < 2);
      U.u[0] = hi ? Ah0 : Al0;
      U.u[1] = hi ? Ah1 : Al1;
      U.u[2] = hi ? Bh0 : Bl0;
      U.u[3] = hi ? Bh1 : Bl1;
      ubf = U.v;
    }
    // attn frags (hi/lo of fp32 attn)
    f16x8 aah, aal;
#pragma unroll
    for (int j = 0; j < 8; j++) {
      float a = attn_lds[lc][qh * 8 + j];
      f16 ahh = (f16)a;
      aah[j] = ahh;
      aal[j] = (f16)(a - (float)ahh);
    }
#pragma unroll
    for (int r = 0; r < 4; r++) acc_o[r] *= QSCALE;
    acc_o = MFMA32(aah, ubf, acc_o);
    acc_o = MFMA32(aal, ubf, acc_o);
#pragma unroll
    for (int r = 0; r < 4; r++)
      ob[(size_t)(n * 16 + quad * 4 + r) * 256 + v0 + lc] = acc_o[r];
    // S += kT @ u_adj  (depth 2 per tile, 8 independent tiles)
#pragma unroll
    for (int dt = 0; dt < 8; dt++) {
      f16x8 kah = *(const f16x8*)&kTH_lds[(dt * 16 + lc) * 24 + qh * 8];
      f16x8 kal = *(const f16x8*)&kTL_lds[(dt * 16 + lc) * 24 + qh * 8];
      accS[dt] = MFMA32(kah, ubf, accS[dt]);
      accS[dt] = MFMA32(kal, ubf, accS[dt]);
    }
    if (n + 1 < NCHUNK) COMMIT();   // waits prefetch, writes staging for n+1
  }
#undef ISSUE
#undef COMMIT
}

// ---------------------------------------------------------------------------
// 7) Gated RMSNorm -> on f16 (o now bh-major)
// ---------------------------------------------------------------------------
__global__ __launch_bounds__(256) void gate_kernel(
    const float* __restrict__ o1, const float* __restrict__ o2,
    const f16* __restrict__ qkvgHi, const float* __restrict__ norm_w,
    f16* __restrict__ onh) {
  int h = threadIdx.x >> 6, lane = threadIdx.x & 63;
  int r = blockIdx.x;              // b*L + l
  int b = r >> 11, l = r & 2047;
  int bh = b * 4 + h;
  const float* orow = ((bh < 12) ? (o1 + (size_t)bh * 524288)
                                 : (o2 + (size_t)(bh - 12) * 524288)) + (size_t)l * 256;
  int v = lane * 4;
  floatx4 ov = *(const floatx4*)&orow[v];
  float ss = ov[0] * ov[0] + ov[1] * ov[1] + ov[2] * ov[2] + ov[3] * ov[3];
  for (int m = 32; m > 0; m >>= 1) ss += __shfl_xor(ss, m);
  float rms = rsqrtf(ss * (1.0f / 256.0f) + 1e-5f);
  size_t goff = (size_t)r * 3072 + 2048 + h * 256 + v;
  floatx4 nw = *(const floatx4*)&norm_w[v];
  f16 outv[4] __attribute__((aligned(8)));
#pragma unroll
  for (int q2 = 0; q2 < 4; q2++) {
    float g = (float)qkvgHi[goff + q2];
    outv[q2] = (f16)(ov[q2] * rms * nw[q2] * (g * sigmoidf_(g)));
  }
  *(uint2*)&onh[(size_t)r * 1024 + h * 256 + v] = *(const uint2*)outv;
}

// ---------------------------------------------------------------------------
extern "C" void kernel_launch(void* const* d_in, const int* in_sizes, int n_in,
                              void* d_out, int out_size, void* d_ws, size_t ws_size,
                              hipStream_t stream) {
  (void)in_sizes; (void)n_in; (void)out_size; (void)ws_size;
  const float* hs     = (const float*)d_in[0];
  const float* conv_w = (const float*)d_in[1];
  const float* Wq     = (const float*)d_in[2];
  const float* Wk     = (const float*)d_in[3];
  const float* Wv     = (const float*)d_in[4];
  const float* Wb     = (const float*)d_in[5];
  const float* Wg     = (const float*)d_in[6];
  const float* Wo     = (const float*)d_in[7];
  const float* norm_w = (const float*)d_in[8];
  float* out = (float*)d_out;

  char* ws = (char*)d_ws;
  f16*   x_hi    = (f16*)(ws + 0);            // 16,777,216  -> uHi after GEMM1
  f16*   x_lo    = (f16*)(ws + 16777216);     // 16,777,216  -> uLo after GEMM1
  f16*   uHi     = (f16*)(ws + 0);
  f16*   uLo     = (f16*)(ws + 16777216);
  f16*   WcatHi  = (f16*)(ws + 33554432);     //  6,291,456  -> o2f after
  float* o2f     = (float*)(ws + 33554432);   //  8,388,608  (bh 12..15)
  f16*   WcatLo  = (f16*)(ws + 39845888);     //  3,145,728  (kv rows only)
  f16*   WoHi    = (f16*)(ws + 42991616);     //  2,097,152
  float* betaf   = (float*)(ws + 45088768);   //    131,072
  f16*   qkvgHi  = (f16*)(ws + 45219840);     // 50,331,648  [8192][3072]
  f16*   kvLo    = (f16*)(ws + 95551488);     // 25,165,824  -> o1f after
  float* o1f     = (float*)(ws + 95551488);   // 25,165,824  (bh 0..11)
  f16*   wHi     = (f16*)(ws + 120717312);    //  8,388,608  -> on_h after scan
  f16*   on_h    = (f16*)(ws + 120717312);    // 16,777,216
  f16*   wLo     = (f16*)(ws + 129105920);    //  8,388,608
  f16*   kTHi    = (f16*)(ws + 137494528);    //  8,388,608
  f16*   kTLo    = (f16*)(ws + 145883136);    //  8,388,608
  float* attnf   = (float*)(ws + 154271744);  //  2,097,152  -> total 156,368,896

  wconv_kernel<<<2048, 256, 0, stream>>>(Wq, Wk, Wv, Wg, Wo, WcatHi, WcatLo, WoHi);
  conv_kernel<<<ROWS, 256, 0, stream>>>(hs, conv_w, x_hi, x_lo);
  beta_kernel<<<ROWS, 256, 0, stream>>>(x_hi, x_lo, Wb, betaf);
  gemm_hilo_kv<<<dim3(12, 64), 256, 0, stream>>>(
      x_hi, x_lo, WcatHi, WcatLo, qkvgHi, kvLo, 1024);
  gemm_plain<1><<<dim3(12, 64), 256, 0, stream>>>(
      x_hi, WcatHi + (size_t)1536 * 1024, qkvgHi + 1536, nullptr, 1024, 3072);
  prepass_kernel<<<16 * NCHUNK, 256, 0, stream>>>(
      qkvgHi, kvLo, betaf, wHi, wLo, kTHi, kTLo, uHi, uLo, attnf);
  scan_kernel<<<256, 64, 0, stream>>>(
      qkvgHi, wHi, wLo, kTHi, kTLo, attnf, uHi, uLo, o1f, o2f);
  gate_kernel<<<ROWS, 256, 0, stream>>>(o1f, o2f, qkvgHi, norm_w, on_h);
  gemm_plain<0><<<dim3(8, 64), 256, 0, stream>>>(
      on_h, WoHi, nullptr, out, 1024, 1024);
}